// Round 1
// baseline (1040.764 us; speedup 1.0000x reference)
//
#include <hip/hip_runtime.h>
#include <hip/hip_bf16.h>
#include <math.h>

// ---------------------------------------------------------------------------
// Problem: VQ power-feature quantizer + 6-layer ReLU MLP.
//   x [1024,512] f32 -> flat N=524288
//   ind[n] = argmin_k ( sum_e(v^e) + sum_j(embW[k][j]^2) - 2*sum_e v^(e+1)*embW[k][e] )
//   q[b][d] = ind[d*1024 + b]   (faithful .view_as(x.T).T scramble)
//   h = relu(q @ W_in^T + b_in); 4x h = relu(h @ W_h^T + b_h);
//   f = relu(h @ W_out^T + b_out)
// Out: f (524288 f32) ++ scalar 0.0f
// ---------------------------------------------------------------------------

#define B_ROWS 1024
#define D_IN   512
#define NTOT   (B_ROWS * D_IN)
#define NCODE  256
#define EDIM   8

// ---------------- quantize: one thread per flat element ---------------------
__global__ __launch_bounds__(256) void quantize_kernel(
    const float* __restrict__ x, const float* __restrict__ embW,
    float* __restrict__ q, float* __restrict__ loss_out)
{
    __shared__ float sW[NCODE][EDIM];   // 8KB, rows 32B-aligned
    __shared__ float sE[NCODE];

    const int tid = threadIdx.x;
    // stage codebook
    for (int i = tid; i < NCODE * EDIM; i += 256)
        ((float*)sW)[i] = embW[i];
    __syncthreads();
    {
        // emb2[k] via numpy pairwise order: ((s0+s1)+(s2+s3))+((s4+s5)+(s6+s7))
        const float* w = sW[tid];
        float s0 = __fmul_rn(w[0], w[0]), s1 = __fmul_rn(w[1], w[1]);
        float s2 = __fmul_rn(w[2], w[2]), s3 = __fmul_rn(w[3], w[3]);
        float s4 = __fmul_rn(w[4], w[4]), s5 = __fmul_rn(w[5], w[5]);
        float s6 = __fmul_rn(w[6], w[6]), s7 = __fmul_rn(w[7], w[7]);
        float a = __fadd_rn(__fadd_rn(s0, s1), __fadd_rn(s2, s3));
        float b = __fadd_rn(__fadd_rn(s4, s5), __fadd_rn(s6, s7));
        sE[tid] = __fadd_rn(a, b);
    }
    __syncthreads();

    const int n = blockIdx.x * 256 + tid;          // grid covers NTOT exactly
    const float v = x[n];

    float p[EDIM];
    #pragma unroll
    for (int e = 0; e < EDIM; ++e)
        p[e] = powf(v, (float)(e + 1));            // match np.power (f32)

    // sm via numpy pairwise order
    float sm;
    {
        float a = __fadd_rn(__fadd_rn(p[0], p[1]), __fadd_rn(p[2], p[3]));
        float b = __fadd_rn(__fadd_rn(p[4], p[5]), __fadd_rn(p[6], p[7]));
        sm = __fadd_rn(a, b);
    }

    float best = INFINITY;
    int bi = 0;
    for (int k = 0; k < NCODE; ++k) {
        const float4 w0 = *reinterpret_cast<const float4*>(&sW[k][0]);
        const float4 w1 = *reinterpret_cast<const float4*>(&sW[k][4]);
        float dot = 0.f;
        dot = fmaf(p[0], w0.x, dot);
        dot = fmaf(p[1], w0.y, dot);
        dot = fmaf(p[2], w0.z, dot);
        dot = fmaf(p[3], w0.w, dot);
        dot = fmaf(p[4], w1.x, dot);
        dot = fmaf(p[5], w1.y, dot);
        dot = fmaf(p[6], w1.z, dot);
        dot = fmaf(p[7], w1.w, dot);
        // dist = (sm + emb2[k]) - 2*dot, no contraction (matches np temporaries)
        float d = __fsub_rn(__fadd_rn(sm, sE[k]), __fmul_rn(2.0f, dot));
        if (d < best) { best = d; bi = k; }        // first-index-wins ties
    }

    // q[b][d] = ind[d*B + b]  ->  this n lands at b = n%1024, d = n/1024
    const int bo = n & (B_ROWS - 1);
    const int dd = n >> 10;
    q[bo * D_IN + dd] = (float)bi;

    if (blockIdx.x == 0 && tid == 0) loss_out[0] = 0.0f;
}

// ---------------- fused GEMM + bias + ReLU (f32 vector) ---------------------
// C[m][n] = relu( sum_k A[m*K+k] * W[n*K+k] + bias[n] )
// BM=64, BN=128, BK=16; 256 threads; 4x8 per thread.
#define BM 64
#define BN 128
#define BK 16

__global__ __launch_bounds__(256) void gemm_bias_relu(
    const float* __restrict__ A, const float* __restrict__ W,
    const float* __restrict__ bias, float* __restrict__ C,
    int M, int N, int K)
{
    __shared__ float As[BK][BM + 4];
    __shared__ float Ws[BK][BN + 4];

    const int tid = threadIdx.x;
    const int bm = blockIdx.y * BM;
    const int bn = blockIdx.x * BN;
    const int tx = tid & 15;        // 0..15 -> n-groups of 8
    const int ty = tid >> 4;        // 0..15 -> m-groups of 4

    float acc[4][8];
    #pragma unroll
    for (int i = 0; i < 4; ++i)
        #pragma unroll
        for (int j = 0; j < 8; ++j) acc[i][j] = 0.f;

    for (int k0 = 0; k0 < K; k0 += BK) {
        // stage A tile: 64 rows x 16 k = 256 float4 (1/thread), transpose to As[k][m]
        {
            const int r = tid >> 2, kq = (tid & 3) * 4;
            const float4 v = *reinterpret_cast<const float4*>(&A[(size_t)(bm + r) * K + k0 + kq]);
            As[kq + 0][r] = v.x; As[kq + 1][r] = v.y;
            As[kq + 2][r] = v.z; As[kq + 3][r] = v.w;
        }
        // stage W tile: 128 rows x 16 k = 512 float4 (2/thread)
        #pragma unroll
        for (int s = 0; s < 2; ++s) {
            const int t = tid + s * 256;
            const int r = t >> 2, kq = (t & 3) * 4;
            const float4 v = *reinterpret_cast<const float4*>(&W[(size_t)(bn + r) * K + k0 + kq]);
            Ws[kq + 0][r] = v.x; Ws[kq + 1][r] = v.y;
            Ws[kq + 2][r] = v.z; Ws[kq + 3][r] = v.w;
        }
        __syncthreads();

        #pragma unroll
        for (int kk = 0; kk < BK; ++kk) {
            float a[4], w[8];
            #pragma unroll
            for (int i = 0; i < 4; ++i) a[i] = As[kk][ty * 4 + i];
            #pragma unroll
            for (int j = 0; j < 8; ++j) w[j] = Ws[kk][tx * 8 + j];
            #pragma unroll
            for (int i = 0; i < 4; ++i)
                #pragma unroll
                for (int j = 0; j < 8; ++j)
                    acc[i][j] = fmaf(a[i], w[j], acc[i][j]);
        }
        __syncthreads();
    }

    // epilogue: bias + relu
    #pragma unroll
    for (int i = 0; i < 4; ++i) {
        const int m = bm + ty * 4 + i;
        #pragma unroll
        for (int j = 0; j < 8; ++j) {
            const int n = bn + tx * 8 + j;
            float v = acc[i][j] + bias[n];
            C[(size_t)m * N + n] = v > 0.f ? v : 0.f;
        }
    }
}

// ---------------------------------------------------------------------------
extern "C" void kernel_launch(void* const* d_in, const int* in_sizes, int n_in,
                              void* d_out, int out_size, void* d_ws, size_t ws_size,
                              hipStream_t stream)
{
    const float* x     = (const float*)d_in[0];
    const float* emb_W = (const float*)d_in[1];
    const float* W_in  = (const float*)d_in[2];
    const float* b_in  = (const float*)d_in[3];
    const float* W_h   = (const float*)d_in[4];
    const float* b_h   = (const float*)d_in[5];
    const float* W_out = (const float*)d_in[6];
    const float* b_out = (const float*)d_in[7];
    float* out = (float*)d_out;

    // ws layout: q (2MB) | h1 (8MB) | h2 (8MB)
    float* q  = (float*)d_ws;
    float* h1 = q + NTOT;                   // 1024*2048
    float* h2 = h1 + (size_t)B_ROWS * 2048;

    // 1) quantize (also writes the scalar loss = 0 at out[NTOT])
    quantize_kernel<<<NTOT / 256, 256, 0, stream>>>(x, emb_W, q, out + NTOT);

    // 2) h1 = relu(q @ W_in^T + b_in)   M=1024 N=2048 K=512
    {
        dim3 grid(2048 / BN, B_ROWS / BM);
        gemm_bias_relu<<<grid, 256, 0, stream>>>(q, W_in, b_in, h1, B_ROWS, 2048, D_IN);
    }
    // 3) 4x h = relu(h @ W_h^T + b_h)   M=1024 N=2048 K=2048
    {
        dim3 grid(2048 / BN, B_ROWS / BM);
        float* src = h1; float* dst = h2;
        for (int l = 0; l < 4; ++l) {
            gemm_bias_relu<<<grid, 256, 0, stream>>>(src, W_h, b_h, dst, B_ROWS, 2048, 2048);
            float* t = src; src = dst; dst = t;
        }
        // after 4 swaps, result is back in h1
    }
    // 4) f = relu(h1 @ W_out^T + b_out) M=1024 N=512 K=2048 -> d_out
    {
        dim3 grid(512 / BN, B_ROWS / BM);
        gemm_bias_relu<<<grid, 256, 0, stream>>>(h1, W_out, b_out, out, B_ROWS, 512, 2048);
    }
}

// Round 2
// 379.399 us; speedup vs baseline: 2.7432x; 2.7432x over previous
//
#include <hip/hip_runtime.h>
#include <hip/hip_bf16.h>
#include <math.h>

// ---------------------------------------------------------------------------
// VQ quantizer + 6-layer ReLU MLP via split-bf16 MFMA.
//   f32 GEMMs emulated as bf16 hi/lo split: C = Ah*Bh + Ah*Bl + Al*Bh
//   (drops lo*lo ~ 2^-16 rel -- far below the 0.5 absmax noise floor).
//   Layer-1 input q is integers 0..255 -> exact bf16, Al==0 (2 MFMAs).
// ---------------------------------------------------------------------------

#define B_ROWS 1024
#define D_IN   512
#define HDIM   2048
#define NTOT   (B_ROWS * D_IN)
#define NCODE  256
#define EDIM   8

typedef __attribute__((ext_vector_type(8))) short bf16x8;
typedef __attribute__((ext_vector_type(4))) float f32x4;

__device__ inline void gload_lds16(const void* g, void* l) {
    __builtin_amdgcn_global_load_lds(
        (const __attribute__((address_space(1))) void*)g,
        (__attribute__((address_space(3))) void*)l, 16, 0, 0);
}

__device__ inline ushort bf16_hi_bits(float v, float* hi_f) {
    __hip_bfloat16 h = __float2bfloat16(v);
    *hi_f = __bfloat162float(h);
    ushort u; __builtin_memcpy(&u, &h, 2); return u;
}
__device__ inline ushort bf16_bits(float v) {
    __hip_bfloat16 h = __float2bfloat16(v);
    ushort u; __builtin_memcpy(&u, &h, 2); return u;
}

// ---------------- quantize: one thread per flat element ---------------------
__global__ __launch_bounds__(256) void quantize_kernel(
    const float* __restrict__ x, const float* __restrict__ embW,
    ushort* __restrict__ qhi, float* __restrict__ loss_out)
{
    __shared__ float sW[NCODE][EDIM];
    __shared__ float sE[NCODE];

    const int tid = threadIdx.x;
    for (int i = tid; i < NCODE * EDIM; i += 256)
        ((float*)sW)[i] = embW[i];
    __syncthreads();
    {   // emb2[k], numpy pairwise order
        const float* w = sW[tid];
        float s0 = __fmul_rn(w[0], w[0]), s1 = __fmul_rn(w[1], w[1]);
        float s2 = __fmul_rn(w[2], w[2]), s3 = __fmul_rn(w[3], w[3]);
        float s4 = __fmul_rn(w[4], w[4]), s5 = __fmul_rn(w[5], w[5]);
        float s6 = __fmul_rn(w[6], w[6]), s7 = __fmul_rn(w[7], w[7]);
        float a = __fadd_rn(__fadd_rn(s0, s1), __fadd_rn(s2, s3));
        float b = __fadd_rn(__fadd_rn(s4, s5), __fadd_rn(s6, s7));
        sE[tid] = __fadd_rn(a, b);
    }
    __syncthreads();

    const int n = blockIdx.x * 256 + tid;
    const float v = x[n];

    float p[EDIM];
    #pragma unroll
    for (int e = 0; e < EDIM; ++e)
        p[e] = powf(v, (float)(e + 1));            // match np.power f32

    float sm;
    {
        float a = __fadd_rn(__fadd_rn(p[0], p[1]), __fadd_rn(p[2], p[3]));
        float b = __fadd_rn(__fadd_rn(p[4], p[5]), __fadd_rn(p[6], p[7]));
        sm = __fadd_rn(a, b);
    }

    float best = INFINITY;
    int bi = 0;
    for (int k = 0; k < NCODE; ++k) {
        const float4 w0 = *reinterpret_cast<const float4*>(&sW[k][0]);
        const float4 w1 = *reinterpret_cast<const float4*>(&sW[k][4]);
        float dot = 0.f;
        dot = fmaf(p[0], w0.x, dot); dot = fmaf(p[1], w0.y, dot);
        dot = fmaf(p[2], w0.z, dot); dot = fmaf(p[3], w0.w, dot);
        dot = fmaf(p[4], w1.x, dot); dot = fmaf(p[5], w1.y, dot);
        dot = fmaf(p[6], w1.z, dot); dot = fmaf(p[7], w1.w, dot);
        float d = __fsub_rn(__fadd_rn(sm, sE[k]), __fmul_rn(2.0f, dot));
        if (d < best) { best = d; bi = k; }        // first-index-wins
    }

    // q[b][d] = ind[d*B + b]; this n -> b = n&1023, d = n>>10. 0..255 exact bf16.
    const int bo = n & (B_ROWS - 1);
    const int dd = n >> 10;
    qhi[bo * D_IN + dd] = bf16_bits((float)bi);

    if (blockIdx.x == 0 && tid == 0) loss_out[0] = 0.0f;
}

// ---------------- f32 -> bf16 hi/lo plane split ------------------------------
__global__ __launch_bounds__(256) void split_f32(
    const float* __restrict__ src, ushort* __restrict__ hi,
    ushort* __restrict__ lo, int n4)
{
    int i = blockIdx.x * 256 + threadIdx.x;
    if (i >= n4) return;
    float4 v = reinterpret_cast<const float4*>(src)[i];
    float f[4] = {v.x, v.y, v.z, v.w};
    ushort hh[4], ll[4];
    #pragma unroll
    for (int j = 0; j < 4; ++j) {
        float hf;
        hh[j] = bf16_hi_bits(f[j], &hf);
        ll[j] = bf16_bits(f[j] - hf);
    }
    ushort4 h = {hh[0], hh[1], hh[2], hh[3]};
    ushort4 l = {ll[0], ll[1], ll[2], ll[3]};
    reinterpret_cast<ushort4*>(hi)[i] = h;
    reinterpret_cast<ushort4*>(lo)[i] = l;
}

// ---------------- split-bf16 MFMA GEMM + bias + ReLU -------------------------
// C[m][n] = relu(sum_k A[m][k]*W[n][k] + bias[n]);  A = Ah+Al, W = Wh+Wl.
// BM=64 fixed. BN templated (128 mid / 64 last). 2 x NWN waves, wave tile 32x32.
// BK=32, global_load_lds(16B), XOR chunk swizzle (chunk ^= (row>>1)&3, 64B rows).
template<int BN, int NWN, bool ALO, bool SPLIT_OUT>
__global__ __launch_bounds__(NWN * 128) void gemm_split(
    const ushort* __restrict__ Ahi, const ushort* __restrict__ Alo,
    const ushort* __restrict__ Whi, const ushort* __restrict__ Wlo,
    const float* __restrict__ bias,
    ushort* __restrict__ Ohi, ushort* __restrict__ Olo,
    float* __restrict__ OF, int N, int K)
{
    constexpr int NWAVES = 2 * NWN;
    constexpr int NBSEG  = BN / 16;           // 1KB segments per B plane tile
    constexpr int AEND   = ALO ? 8 : 4;
    constexpr int NSEG   = AEND + 2 * NBSEG;
    constexpr int OFF_AH = 0;
    constexpr int OFF_AL = 4096;
    constexpr int OFF_BH = ALO ? 8192 : 4096;
    constexpr int OFF_BL = OFF_BH + BN * 64;
    constexpr int LDS_SZ = OFF_BL + BN * 64;
    __shared__ char lds[LDS_SZ];

    const int tid  = threadIdx.x;
    const int lane = tid & 63;
    const int wid  = tid >> 6;

    // bijective XCD swizzle; column-major tile order so same-XCD blocks share
    // a weight panel (fits 4MB per-XCD L2).
    const int gx = gridDim.x, gy = gridDim.y;
    int id  = blockIdx.y * gx + blockIdx.x;
    int cpx = (gx * gy) >> 3;                 // grids are multiples of 8
    int sw  = (id & 7) * cpx + (id >> 3);
    int bxt = sw / gy, byt = sw - bxt * gy;
    const int bm = byt * 64, bn = bxt * BN;

    const int wm = (wid / NWN) * 32, wn = (wid % NWN) * 32;

    f32x4 acc[2][2] = {};

    for (int k0 = 0; k0 < K; k0 += 32) {
        // ---- stage 4 tiles via global_load_lds, pre-swizzled source ----
        for (int s = wid; s < NSEG; s += NWAVES) {
            const ushort* pl; int row0, base, kb;
            if (s < 4)                 { pl = Ahi; row0 = bm; base = OFF_AH; kb = s; }
            else if (ALO && s < 8)     { pl = Alo; row0 = bm; base = OFF_AL; kb = s - 4; }
            else {
                int t = s - AEND;
                if (t < NBSEG) { pl = Whi; row0 = bn; base = OFF_BH; kb = t; }
                else           { pl = Wlo; row0 = bn; base = OFF_BL; kb = t - NBSEG; }
            }
            int r  = kb * 16 + (lane >> 2);
            int ch = (lane & 3) ^ ((r >> 1) & 3);
            gload_lds16(pl + (size_t)(row0 + r) * K + k0 + ch * 8,
                        lds + base + kb * 1024);
        }
        __syncthreads();

        // ---- fragments (swizzled ds_read_b128) ----
        bf16x8 aH[2], aL[2], bH[2], bL[2];
        #pragma unroll
        for (int f = 0; f < 2; ++f) {
            int ar  = wm + f * 16 + (lane & 15);
            int off = ar * 64 + (((lane >> 4) ^ ((ar >> 1) & 3)) << 4);
            aH[f] = *(const bf16x8*)(lds + OFF_AH + off);
            if constexpr (ALO) aL[f] = *(const bf16x8*)(lds + OFF_AL + off);
        }
        #pragma unroll
        for (int f = 0; f < 2; ++f) {
            int br  = wn + f * 16 + (lane & 15);
            int off = br * 64 + (((lane >> 4) ^ ((br >> 1) & 3)) << 4);
            bH[f] = *(const bf16x8*)(lds + OFF_BH + off);
            bL[f] = *(const bf16x8*)(lds + OFF_BL + off);
        }

        // ---- MFMAs, term-major so same-acc chains are 4 apart ----
        #pragma unroll
        for (int fm = 0; fm < 2; ++fm)
            #pragma unroll
            for (int fn = 0; fn < 2; ++fn)
                acc[fm][fn] = __builtin_amdgcn_mfma_f32_16x16x32_bf16(
                    aH[fm], bH[fn], acc[fm][fn], 0, 0, 0);
        #pragma unroll
        for (int fm = 0; fm < 2; ++fm)
            #pragma unroll
            for (int fn = 0; fn < 2; ++fn)
                acc[fm][fn] = __builtin_amdgcn_mfma_f32_16x16x32_bf16(
                    aH[fm], bL[fn], acc[fm][fn], 0, 0, 0);
        if constexpr (ALO) {
            #pragma unroll
            for (int fm = 0; fm < 2; ++fm)
                #pragma unroll
                for (int fn = 0; fn < 2; ++fn)
                    acc[fm][fn] = __builtin_amdgcn_mfma_f32_16x16x32_bf16(
                        aL[fm], bH[fn], acc[fm][fn], 0, 0, 0);
        }
        __syncthreads();
    }

    // ---- epilogue: bias + ReLU; C row=(l>>4)*4+reg, col=l&15 (m89 layout) ----
    #pragma unroll
    for (int fm = 0; fm < 2; ++fm) {
        #pragma unroll
        for (int fn = 0; fn < 2; ++fn) {
            const int col  = bn + wn + fn * 16 + (lane & 15);
            const float bc = bias[col];
            #pragma unroll
            for (int r = 0; r < 4; ++r) {
                const int row = bm + wm + fm * 16 + ((lane >> 4) << 2) + r;
                float v = acc[fm][fn][r] + bc;
                v = v > 0.f ? v : 0.f;
                if constexpr (SPLIT_OUT) {
                    float hf;
                    ushort hb = bf16_hi_bits(v, &hf);
                    Ohi[(size_t)row * N + col] = hb;
                    Olo[(size_t)row * N + col] = bf16_bits(v - hf);
                } else {
                    OF[(size_t)row * N + col] = v;
                }
            }
        }
    }
}

// ---------------------------------------------------------------------------
extern "C" void kernel_launch(void* const* d_in, const int* in_sizes, int n_in,
                              void* d_out, int out_size, void* d_ws, size_t ws_size,
                              hipStream_t stream)
{
    const float* x     = (const float*)d_in[0];
    const float* emb_W = (const float*)d_in[1];
    const float* W_in  = (const float*)d_in[2];
    const float* b_in  = (const float*)d_in[3];
    const float* W_h   = (const float*)d_in[4];
    const float* b_h   = (const float*)d_in[5];
    const float* W_out = (const float*)d_in[6];
    const float* b_out = (const float*)d_in[7];
    float* out = (float*)d_out;

    char* w = (char*)d_ws;
    const size_t MB = 1 << 20;
    ushort* qhi  = (ushort*)(w);            // 1MB
    ushort* h1hi = (ushort*)(w + 1*MB);     // 4MB each
    ushort* h1lo = (ushort*)(w + 5*MB);
    ushort* h2hi = (ushort*)(w + 9*MB);
    ushort* h2lo = (ushort*)(w + 13*MB);
    ushort* wihi = (ushort*)(w + 17*MB);    // 2MB each
    ushort* wilo = (ushort*)(w + 19*MB);
    ushort* whhi = (ushort*)(w + 21*MB);    // 8MB each
    ushort* whlo = (ushort*)(w + 29*MB);
    ushort* wohi = (ushort*)(w + 37*MB);    // 2MB each
    ushort* wolo = (ushort*)(w + 39*MB);    // total 41MB

    // weight plane splits
    split_f32<<<(HDIM * D_IN / 4 + 255) / 256, 256, 0, stream>>>(W_in,  wihi, wilo, HDIM * D_IN / 4);
    split_f32<<<(HDIM * HDIM / 4 + 255) / 256, 256, 0, stream>>>(W_h,   whhi, whlo, HDIM * HDIM / 4);
    split_f32<<<(D_IN * HDIM / 4 + 255) / 256, 256, 0, stream>>>(W_out, wohi, wolo, D_IN * HDIM / 4);

    // quantize (writes scalar loss = 0 at out[NTOT])
    quantize_kernel<<<NTOT / 256, 256, 0, stream>>>(x, emb_W, qhi, out + NTOT);

    // L1: h1 = relu(q @ W_in^T + b_in)   M=1024 N=2048 K=512  (A exact, no Alo)
    gemm_split<128, 4, false, true><<<dim3(HDIM / 128, B_ROWS / 64), 512, 0, stream>>>(
        qhi, nullptr, wihi, wilo, b_in, h1hi, h1lo, nullptr, HDIM, D_IN);

    // 4x mid: h = relu(h @ W_h^T + b_h)  M=1024 N=2048 K=2048
    ushort *shi = h1hi, *slo = h1lo, *dhi = h2hi, *dlo = h2lo;
    for (int l = 0; l < 4; ++l) {
        gemm_split<128, 4, true, true><<<dim3(HDIM / 128, B_ROWS / 64), 512, 0, stream>>>(
            shi, slo, whhi, whlo, b_h, dhi, dlo, nullptr, HDIM, HDIM);
        ushort* t;
        t = shi; shi = dhi; dhi = t;
        t = slo; slo = dlo; dlo = t;
    }
    // result now back in h1 planes (shi/slo)

    // L6: f = relu(h @ W_out^T + b_out)  M=1024 N=512 K=2048 -> d_out (f32)
    gemm_split<64, 2, true, false><<<dim3(D_IN / 64, B_ROWS / 64), 256, 0, stream>>>(
        shi, slo, wohi, wolo, b_out, nullptr, nullptr, out, D_IN, HDIM);
}

// Round 3
// 224.269 us; speedup vs baseline: 4.6407x; 1.6917x over previous
//
#include <hip/hip_runtime.h>
#include <hip/hip_bf16.h>
#include <math.h>

// ---------------------------------------------------------------------------
// VQ quantizer + 6-layer ReLU MLP via split-bf16 MFMA.
//   f32 GEMM ~= Ah*Bh + Ah*Bl + Al*Bh  (drop lo*lo ~2^-16 rel)
//   R3: 2-phase double-buffered pipeline (stage-next BEFORE compute, single
//   __syncthreads per K-step), wave tile 32x64, BK=64, split-K=4 for L6.
// ---------------------------------------------------------------------------

#define B_ROWS 1024
#define D_IN   512
#define HDIM   2048
#define NTOT   (B_ROWS * D_IN)
#define NCODE  256
#define EDIM   8

typedef __attribute__((ext_vector_type(8))) short bf16x8;
typedef __attribute__((ext_vector_type(4))) float f32x4;

__device__ inline void gload_lds16(const void* g, void* l) {
    __builtin_amdgcn_global_load_lds(
        (const __attribute__((address_space(1))) void*)g,
        (__attribute__((address_space(3))) void*)l, 16, 0, 0);
}

__device__ inline ushort bf16_hi_bits(float v, float* hi_f) {
    __hip_bfloat16 h = __float2bfloat16(v);
    *hi_f = __bfloat162float(h);
    ushort u; __builtin_memcpy(&u, &h, 2); return u;
}
__device__ inline ushort bf16_bits(float v) {
    __hip_bfloat16 h = __float2bfloat16(v);
    ushort u; __builtin_memcpy(&u, &h, 2); return u;
}

// ---------------- quantize: one thread per flat element ---------------------
__global__ __launch_bounds__(256) void quantize_kernel(
    const float* __restrict__ x, const float* __restrict__ embW,
    ushort* __restrict__ qhi, float* __restrict__ loss_out)
{
    __shared__ float sW[NCODE][EDIM];
    __shared__ float sE[NCODE];

    const int tid = threadIdx.x;
    for (int i = tid; i < NCODE * EDIM; i += 256)
        ((float*)sW)[i] = embW[i];
    __syncthreads();
    {   // emb2[k], numpy pairwise order
        const float* w = sW[tid];
        float s0 = __fmul_rn(w[0], w[0]), s1 = __fmul_rn(w[1], w[1]);
        float s2 = __fmul_rn(w[2], w[2]), s3 = __fmul_rn(w[3], w[3]);
        float s4 = __fmul_rn(w[4], w[4]), s5 = __fmul_rn(w[5], w[5]);
        float s6 = __fmul_rn(w[6], w[6]), s7 = __fmul_rn(w[7], w[7]);
        float a = __fadd_rn(__fadd_rn(s0, s1), __fadd_rn(s2, s3));
        float b = __fadd_rn(__fadd_rn(s4, s5), __fadd_rn(s6, s7));
        sE[tid] = __fadd_rn(a, b);
    }
    __syncthreads();

    const int n = blockIdx.x * 256 + tid;
    const float v = x[n];

    float p[EDIM];
    #pragma unroll
    for (int e = 0; e < EDIM; ++e)
        p[e] = powf(v, (float)(e + 1));            // match np.power f32

    float sm;
    {
        float a = __fadd_rn(__fadd_rn(p[0], p[1]), __fadd_rn(p[2], p[3]));
        float b = __fadd_rn(__fadd_rn(p[4], p[5]), __fadd_rn(p[6], p[7]));
        sm = __fadd_rn(a, b);
    }

    float best = INFINITY;
    int bi = 0;
    for (int k = 0; k < NCODE; ++k) {
        const float4 w0 = *reinterpret_cast<const float4*>(&sW[k][0]);
        const float4 w1 = *reinterpret_cast<const float4*>(&sW[k][4]);
        float dot = 0.f;
        dot = fmaf(p[0], w0.x, dot); dot = fmaf(p[1], w0.y, dot);
        dot = fmaf(p[2], w0.z, dot); dot = fmaf(p[3], w0.w, dot);
        dot = fmaf(p[4], w1.x, dot); dot = fmaf(p[5], w1.y, dot);
        dot = fmaf(p[6], w1.z, dot); dot = fmaf(p[7], w1.w, dot);
        float d = __fsub_rn(__fadd_rn(sm, sE[k]), __fmul_rn(2.0f, dot));
        if (d < best) { best = d; bi = k; }        // first-index-wins
    }

    const int bo = n & (B_ROWS - 1);
    const int dd = n >> 10;
    qhi[bo * D_IN + dd] = bf16_bits((float)bi);    // ints 0..255 exact in bf16

    if (blockIdx.x == 0 && tid == 0) loss_out[0] = 0.0f;
}

// ---------------- merged f32 -> bf16 hi/lo plane split -----------------------
__global__ __launch_bounds__(256) void split_all(
    const float* __restrict__ Wi, const float* __restrict__ Wh,
    const float* __restrict__ Wo,
    ushort* __restrict__ wihi, ushort* __restrict__ wilo,
    ushort* __restrict__ whhi, ushort* __restrict__ whlo,
    ushort* __restrict__ wohi, ushort* __restrict__ wolo)
{
    const int i = blockIdx.x * 256 + threadIdx.x;
    const int R0 = HDIM * D_IN / 4;        // 262144
    const int R1 = R0 + HDIM * HDIM / 4;   // 1310720
    const float* src; ushort* hi; ushort* lo; int j;
    if (i < R0)      { src = Wi; hi = wihi; lo = wilo; j = i; }
    else if (i < R1) { src = Wh; hi = whhi; lo = whlo; j = i - R0; }
    else             { src = Wo; hi = wohi; lo = wolo; j = i - R1; }
    float4 v = reinterpret_cast<const float4*>(src)[j];
    float f[4] = {v.x, v.y, v.z, v.w};
    ushort hh[4], ll[4];
    #pragma unroll
    for (int c = 0; c < 4; ++c) {
        float hf;
        hh[c] = bf16_hi_bits(f[c], &hf);
        ll[c] = bf16_bits(f[c] - hf);
    }
    ushort4 h = {hh[0], hh[1], hh[2], hh[3]};
    ushort4 l = {ll[0], ll[1], ll[2], ll[3]};
    reinterpret_cast<ushort4*>(hi)[j] = h;
    reinterpret_cast<ushort4*>(lo)[j] = l;
}

// ---------------- split-bf16 MFMA GEMM, 2-phase pipeline ---------------------
// Block 64x128, 4 waves, wave 32x64, BK=64, double-buffered LDS (2x48KB).
// PARTIAL: write raw f32 partials at [kz*1024+row][col] (split-K), no bias.
template<bool ALO, bool PARTIAL>
__global__ __launch_bounds__(256) void gemm_split(
    const ushort* __restrict__ Ahi, const ushort* __restrict__ Alo,
    const ushort* __restrict__ Whi, const ushort* __restrict__ Wlo,
    const float* __restrict__ bias,
    ushort* __restrict__ Ohi, ushort* __restrict__ Olo,
    float* __restrict__ OF, int N, int K, int klen)
{
    constexpr int BUF = 49152;
    constexpr int OFF_AH = 0, OFF_AL = 8192, OFF_BH = 16384;
    __shared__ char lds[2 * BUF];

    const int tid = threadIdx.x, lane = tid & 63, wid = tid >> 6;

    // bijective XCD swizzle over column-major linearization
    const int gy = gridDim.y;
    const int nwg = gridDim.x * gy;
    int lin = blockIdx.x * gy + blockIdx.y;
    int q   = nwg >> 3;
    int sw  = (lin & 7) * q + (lin >> 3);
    int bx  = sw / gy, by2 = sw % gy;
    const int bm   = (by2 & 15) << 6;
    const int kz   = by2 >> 4;
    const int kbeg = kz * klen;
    const int bn   = bx << 7;

    const int wm = (wid >> 1) << 5;   // 0,32
    const int wn = (wid & 1) << 6;    // 0,64

    // ---- precompute per-wave stage pointers (seg = 1KB = 8 rows x 128B) ----
    constexpr int NSEGW = ALO ? 12 : 10;     // 48 or 40 segs / 4 waves
    const ushort* gp[NSEGW];
    uint ldsoff[NSEGW];
    #pragma unroll
    for (int i = 0; i < NSEGW; ++i) {
        int s = wid + i * 4;
        const ushort* pl; int row0, base, sip;
        if (ALO) {
            if (s < 8)       { pl = Ahi; row0 = bm; base = OFF_AH;         sip = s; }
            else if (s < 16) { pl = Alo; row0 = bm; base = OFF_AL;         sip = s - 8; }
            else if (s < 32) { pl = Whi; row0 = bn; base = OFF_BH;         sip = s - 16; }
            else             { pl = Wlo; row0 = bn; base = OFF_BH + 16384; sip = s - 32; }
        } else {
            if (s < 8)       { pl = Ahi; row0 = bm; base = OFF_AH;         sip = s; }
            else if (s < 24) { pl = Whi; row0 = bn; base = OFF_BH;         sip = s - 8; }
            else             { pl = Wlo; row0 = bn; base = OFF_BH + 16384; sip = s - 24; }
        }
        int r  = sip * 8 + (lane >> 3);
        int ch = (lane & 7) ^ (r & 7);          // pre-swizzled source
        gp[i]     = pl + (size_t)(row0 + r) * K + kbeg + ch * 8;
        ldsoff[i] = base + sip * 1024;          // linear DMA dest
    }

    // ---- fragment LDS offsets (swizzled ds_read_b128) ----
    uint aoff[2][2], boff[4][2];
    #pragma unroll
    for (int f = 0; f < 2; ++f) {
        int ar = wm + f * 16 + (lane & 15);
        #pragma unroll
        for (int s = 0; s < 2; ++s) {
            int ch = (s * 4 + (lane >> 4)) ^ (ar & 7);
            aoff[f][s] = OFF_AH + ar * 128 + ch * 16;
        }
    }
    #pragma unroll
    for (int f = 0; f < 4; ++f) {
        int br = wn + f * 16 + (lane & 15);
        #pragma unroll
        for (int s = 0; s < 2; ++s) {
            int ch = (s * 4 + (lane >> 4)) ^ (br & 7);
            boff[f][s] = OFF_BH + br * 128 + ch * 16;
        }
    }

    auto stage = [&](int kt, int b) {
        #pragma unroll
        for (int i = 0; i < NSEGW; ++i)
            gload_lds16(gp[i] + kt * 64, lds + b * BUF + ldsoff[i]);
    };

    f32x4 acc[2][4] = {};
    const int NT = klen >> 6;

    stage(0, 0);
    __syncthreads();

    for (int t = 0; t < NT; ++t) {
        const int cur = t & 1;
        if (t + 1 < NT) stage(t + 1, cur ^ 1);   // issue next tile's DMA first

        const char* lb = lds + cur * BUF;
        bf16x8 aH[2][2], aL[2][2], bH[2][4], bL[2][4];
        #pragma unroll
        for (int s = 0; s < 2; ++s) {
            #pragma unroll
            for (int f = 0; f < 2; ++f) {
                aH[s][f] = *(const bf16x8*)(lb + aoff[f][s]);
                if constexpr (ALO) aL[s][f] = *(const bf16x8*)(lb + aoff[f][s] + 8192);
            }
            #pragma unroll
            for (int f = 0; f < 4; ++f) {
                bH[s][f] = *(const bf16x8*)(lb + boff[f][s]);
                bL[s][f] = *(const bf16x8*)(lb + boff[f][s] + 16384);
            }
        }
        #pragma unroll
        for (int s = 0; s < 2; ++s) {
            #pragma unroll
            for (int fm = 0; fm < 2; ++fm)
                #pragma unroll
                for (int fn = 0; fn < 4; ++fn)
                    acc[fm][fn] = __builtin_amdgcn_mfma_f32_16x16x32_bf16(
                        aH[s][fm], bH[s][fn], acc[fm][fn], 0, 0, 0);
            #pragma unroll
            for (int fm = 0; fm < 2; ++fm)
                #pragma unroll
                for (int fn = 0; fn < 4; ++fn)
                    acc[fm][fn] = __builtin_amdgcn_mfma_f32_16x16x32_bf16(
                        aH[s][fm], bL[s][fn], acc[fm][fn], 0, 0, 0);
            if constexpr (ALO) {
                #pragma unroll
                for (int fm = 0; fm < 2; ++fm)
                    #pragma unroll
                    for (int fn = 0; fn < 4; ++fn)
                        acc[fm][fn] = __builtin_amdgcn_mfma_f32_16x16x32_bf16(
                            aL[s][fm], bH[s][fn], acc[fm][fn], 0, 0, 0);
            }
        }
        __syncthreads();   // vmcnt(0)+lgkmcnt(0)+barrier: next DMA landed, reads done
    }

    // ---- epilogue; C layout: col=lane&15, row=(lane>>4)*4+r ----
    #pragma unroll
    for (int fm = 0; fm < 2; ++fm) {
        #pragma unroll
        for (int fn = 0; fn < 4; ++fn) {
            const int col = bn + wn + fn * 16 + (lane & 15);
            const int rb  = bm + wm + fm * 16 + ((lane >> 4) << 2);
            if constexpr (PARTIAL) {
                #pragma unroll
                for (int r = 0; r < 4; ++r)
                    OF[(size_t)(kz * B_ROWS + rb + r) * N + col] = acc[fm][fn][r];
            } else {
                const float bc = bias[col];
                #pragma unroll
                for (int r = 0; r < 4; ++r) {
                    float v = acc[fm][fn][r] + bc;
                    v = v > 0.f ? v : 0.f;
                    float hf;
                    ushort hb = bf16_hi_bits(v, &hf);
                    Ohi[(size_t)(rb + r) * N + col] = hb;
                    Olo[(size_t)(rb + r) * N + col] = bf16_bits(v - hf);
                }
            }
        }
    }
}

// ---------------- split-K combine: out = relu(sum_z partial + bias) ----------
__global__ __launch_bounds__(256) void combine_relu(
    const float* __restrict__ part, const float* __restrict__ bias,
    float* __restrict__ out)
{
    const int i = blockIdx.x * 256 + threadIdx.x;     // over 131072 float4
    const float4* p = (const float4*)part;
    float4 a = p[i], b = p[i + 131072], c = p[i + 262144], d = p[i + 393216];
    float4 bb = ((const float4*)bias)[i & 127];
    float4 o;
    o.x = a.x + b.x + c.x + d.x + bb.x;
    o.y = a.y + b.y + c.y + d.y + bb.y;
    o.z = a.z + b.z + c.z + d.z + bb.z;
    o.w = a.w + b.w + c.w + d.w + bb.w;
    o.x = o.x > 0.f ? o.x : 0.f;
    o.y = o.y > 0.f ? o.y : 0.f;
    o.z = o.z > 0.f ? o.z : 0.f;
    o.w = o.w > 0.f ? o.w : 0.f;
    reinterpret_cast<float4*>(out)[i] = o;
}

// ---------------------------------------------------------------------------
extern "C" void kernel_launch(void* const* d_in, const int* in_sizes, int n_in,
                              void* d_out, int out_size, void* d_ws, size_t ws_size,
                              hipStream_t stream)
{
    const float* x     = (const float*)d_in[0];
    const float* emb_W = (const float*)d_in[1];
    const float* W_in  = (const float*)d_in[2];
    const float* b_in  = (const float*)d_in[3];
    const float* W_h   = (const float*)d_in[4];
    const float* b_h   = (const float*)d_in[5];
    const float* W_out = (const float*)d_in[6];
    const float* b_out = (const float*)d_in[7];
    float* out = (float*)d_out;

    char* w = (char*)d_ws;
    const size_t MB = 1 << 20;
    ushort* qhi  = (ushort*)(w);            // 1MB
    ushort* h1hi = (ushort*)(w + 1*MB);     // 4MB each
    ushort* h1lo = (ushort*)(w + 5*MB);
    ushort* h2hi = (ushort*)(w + 9*MB);
    ushort* h2lo = (ushort*)(w + 13*MB);
    float*  partial = (float*)(w + 9*MB);   // 8MB, reuses h2 region (dead by L6)
    ushort* wihi = (ushort*)(w + 17*MB);    // 2MB each
    ushort* wilo = (ushort*)(w + 19*MB);
    ushort* whhi = (ushort*)(w + 21*MB);    // 8MB each
    ushort* whlo = (ushort*)(w + 29*MB);
    ushort* wohi = (ushort*)(w + 37*MB);    // 2MB each
    ushort* wolo = (ushort*)(w + 39*MB);    // total 41MB

    // weight plane splits (one merged launch)
    split_all<<<6144, 256, 0, stream>>>(W_in, W_h, W_out,
                                        wihi, wilo, whhi, whlo, wohi, wolo);

    // quantize (also writes scalar loss = 0 at out[NTOT])
    quantize_kernel<<<NTOT / 256, 256, 0, stream>>>(x, emb_W, qhi, out + NTOT);

    // L1: h1 = relu(q @ W_in^T + b_in)   M=1024 N=2048 K=512  (A exact: 2 terms)
    gemm_split<false, false><<<dim3(16, 16), 256, 0, stream>>>(
        qhi, nullptr, wihi, wilo, b_in, h1hi, h1lo, nullptr, HDIM, D_IN, D_IN);

    // 4x mid: h = relu(h @ W_h^T + b_h)  M=1024 N=2048 K=2048 (3 terms)
    ushort *shi = h1hi, *slo = h1lo, *dhi = h2hi, *dlo = h2lo;
    for (int l = 0; l < 4; ++l) {
        gemm_split<true, false><<<dim3(16, 16), 256, 0, stream>>>(
            shi, slo, whhi, whlo, b_h, dhi, dlo, nullptr, HDIM, HDIM, HDIM);
        ushort* t;
        t = shi; shi = dhi; dhi = t;
        t = slo; slo = dlo; dlo = t;
    }
    // result back in h1 planes (shi/slo == h1hi/h1lo)

    // L6: split-K=4 partials  M=1024 N=512 K=2048, grid (4, 16*4)
    gemm_split<true, true><<<dim3(4, 64), 256, 0, stream>>>(
        shi, slo, wohi, wolo, nullptr, nullptr, nullptr, partial, D_IN, HDIM, D_IN);

    // combine + bias + relu -> d_out
    combine_relu<<<512, 256, 0, stream>>>(partial, b_out, out);
}